// Round 1
// baseline (1712.771 us; speedup 1.0000x reference)
//
#include <hip/hip_runtime.h>
#include <math.h>

#define N_NODES 40000
#define N_EDGES 640000
#define IN_DIM 512
#define HID_DIM 128
#define OUT_DIM 40

// ---------------- zero fill (accumulators) ----------------
__global__ __launch_bounds__(256) void zero_kernel(float* __restrict__ p, int n4) {
    int i = blockIdx.x * 256 + threadIdx.x;
    if (i < n4) {
        reinterpret_cast<float4*>(p)[i] = make_float4(0.f, 0.f, 0.f, 0.f);
    }
}

// ---------------- GEMM1: y1 = x @ W1  (40000x512 @ 512x128) ----------------
// 64x128 tile per block, 256 threads, 4x8 micro-tile per thread, BK=16.
__global__ __launch_bounds__(256) void gemm1_kernel(const float* __restrict__ x,
                                                    const float* __restrict__ W1,
                                                    float* __restrict__ y1) {
    __shared__ float As[16][68];    // [k][m], pad 68: 16B-aligned rows, 2-way max conflict
    __shared__ float Bs[16][128];   // [k][n]
    const int m0 = blockIdx.x * 64;
    const int t  = threadIdx.x;
    const int tx = t & 15;          // col group (8 cols each)
    const int ty = t >> 4;          // row group (4 rows each)
    float acc[4][8] = {};

    for (int k0 = 0; k0 < IN_DIM; k0 += 16) {
        // stage A: 64 rows x 16 k -> one float4 per thread (transposed into LDS)
        {
            int r = t >> 2;
            int c = (t & 3) * 4;
            float4 v = *reinterpret_cast<const float4*>(&x[(m0 + r) * IN_DIM + k0 + c]);
            As[c + 0][r] = v.x; As[c + 1][r] = v.y; As[c + 2][r] = v.z; As[c + 3][r] = v.w;
        }
        // stage B: 16 k x 128 n -> 8 floats per thread
        {
            int e  = t * 8;
            int kk = e >> 7;
            int nn = e & 127;
            const float* src = &W1[(k0 + kk) * HID_DIM + nn];
            float4 v0 = *reinterpret_cast<const float4*>(src);
            float4 v1 = *reinterpret_cast<const float4*>(src + 4);
            *reinterpret_cast<float4*>(&Bs[kk][nn])     = v0;
            *reinterpret_cast<float4*>(&Bs[kk][nn + 4]) = v1;
        }
        __syncthreads();
#pragma unroll
        for (int kk = 0; kk < 16; ++kk) {
            float a[4], b[8];
#pragma unroll
            for (int i = 0; i < 4; ++i) a[i] = As[kk][ty * 4 + i];
            float4 b0 = *reinterpret_cast<const float4*>(&Bs[kk][tx * 8]);
            float4 b1 = *reinterpret_cast<const float4*>(&Bs[kk][tx * 8 + 4]);
            b[0] = b0.x; b[1] = b0.y; b[2] = b0.z; b[3] = b0.w;
            b[4] = b1.x; b[5] = b1.y; b[6] = b1.z; b[7] = b1.w;
#pragma unroll
            for (int i = 0; i < 4; ++i)
#pragma unroll
                for (int j = 0; j < 8; ++j) acc[i][j] += a[i] * b[j];
        }
        __syncthreads();
    }
#pragma unroll
    for (int i = 0; i < 4; ++i) {
        int row = m0 + ty * 4 + i;
        float4 v0 = make_float4(acc[i][0], acc[i][1], acc[i][2], acc[i][3]);
        float4 v1 = make_float4(acc[i][4], acc[i][5], acc[i][6], acc[i][7]);
        *reinterpret_cast<float4*>(&y1[row * HID_DIM + tx * 8])     = v0;
        *reinterpret_cast<float4*>(&y1[row * HID_DIM + tx * 8 + 4]) = v1;
    }
}

// ---------------- SpMM1: hacc[row] += val * y1[col]  (128 feats) ----------------
// 32 threads per edge, float4 per thread, 4 atomicAdds.
__global__ __launch_bounds__(256) void spmm1_kernel(const int* __restrict__ erow,
                                                    const int* __restrict__ ecol,
                                                    const float* __restrict__ eval,
                                                    const float* __restrict__ y1,
                                                    float* __restrict__ hacc) {
    int idx = blockIdx.x * 256 + threadIdx.x;
    int e = idx >> 5;
    int q = (idx & 31) * 4;
    if (e < N_EDGES) {
        int r = erow[e];
        int c = ecol[e];
        float v = eval[e];
        float4 g = *reinterpret_cast<const float4*>(&y1[c * HID_DIM + q]);
        float* dst = &hacc[r * HID_DIM + q];
        atomicAdd(dst + 0, v * g.x);
        atomicAdd(dst + 1, v * g.y);
        atomicAdd(dst + 2, v * g.z);
        atomicAdd(dst + 3, v * g.w);
    }
}

// ---------------- GEMM2: y2 = relu(hacc + b1) @ W2  (40000x128 @ 128x40) ----------------
// 64 rows per block, 64 threads; thread = (row lane 0..15, col group 0..3 of 10 cols),
// 4 rows x 10 cols micro-tile. Bias+ReLU fused into the LDS staging load.
__global__ __launch_bounds__(64) void gemm2_kernel(const float* __restrict__ hacc,
                                                   const float* __restrict__ b1,
                                                   const float* __restrict__ W2,
                                                   float* __restrict__ y2) {
    __shared__ float hs[64][132];          // pad 132 (16B aligned, 2-way max conflict)
    __shared__ float w2s[HID_DIM * OUT_DIM];
    const int m0 = blockIdx.x * 64;
    const int t  = threadIdx.x;

    // stage h tile with fused bias + relu: 8192 floats, 32 float4 per thread
#pragma unroll
    for (int i = 0; i < 32; ++i) {
        int flat = i * 256 + t * 4;
        int row = flat >> 7;
        int col = flat & 127;
        float4 v  = *reinterpret_cast<const float4*>(&hacc[(m0 + row) * HID_DIM + col]);
        float4 vb = *reinterpret_cast<const float4*>(&b1[col]);
        v.x = fmaxf(v.x + vb.x, 0.f);
        v.y = fmaxf(v.y + vb.y, 0.f);
        v.z = fmaxf(v.z + vb.z, 0.f);
        v.w = fmaxf(v.w + vb.w, 0.f);
        *reinterpret_cast<float4*>(&hs[row][col]) = v;
    }
    // stage W2: 5120 floats, 20 float4 per thread
#pragma unroll
    for (int i = 0; i < 20; ++i) {
        int flat = i * 256 + t * 4;
        *reinterpret_cast<float4*>(&w2s[flat]) =
            *reinterpret_cast<const float4*>(&W2[flat]);
    }
    __syncthreads();

    const int rl = t & 15;      // row lane: rows rl + 16*i
    const int g  = t >> 4;      // col group: cols g*10 .. g*10+9
    float acc[4][10] = {};
#pragma unroll 4
    for (int k = 0; k < HID_DIM; ++k) {
        float a[4];
#pragma unroll
        for (int i = 0; i < 4; ++i) a[i] = hs[rl + 16 * i][k];
        float b[10];
#pragma unroll
        for (int j = 0; j < 10; j += 2) {
            float2 w = *reinterpret_cast<const float2*>(&w2s[k * OUT_DIM + g * 10 + j]);
            b[j] = w.x; b[j + 1] = w.y;
        }
#pragma unroll
        for (int i = 0; i < 4; ++i)
#pragma unroll
            for (int j = 0; j < 10; ++j) acc[i][j] += a[i] * b[j];
    }
#pragma unroll
    for (int i = 0; i < 4; ++i) {
        int row = m0 + rl + 16 * i;
#pragma unroll
        for (int j = 0; j < 10; j += 2) {
            float2 v = make_float2(acc[i][j], acc[i][j + 1]);
            *reinterpret_cast<float2*>(&y2[row * OUT_DIM + g * 10 + j]) = v;
        }
    }
}

// ---------------- SpMM2: oacc[row] += val * y2[col]  (40 feats) ----------------
// 10 quad-items per edge.
__global__ __launch_bounds__(256) void spmm2_kernel(const int* __restrict__ erow,
                                                    const int* __restrict__ ecol,
                                                    const float* __restrict__ eval,
                                                    const float* __restrict__ y2,
                                                    float* __restrict__ oacc) {
    int idx = blockIdx.x * 256 + threadIdx.x;
    if (idx < N_EDGES * 10) {
        int e = idx / 10;
        int q = (idx - e * 10) * 4;
        int r = erow[e];
        int c = ecol[e];
        float v = eval[e];
        float4 g = *reinterpret_cast<const float4*>(&y2[c * OUT_DIM + q]);
        float* dst = &oacc[r * OUT_DIM + q];
        atomicAdd(dst + 0, v * g.x);
        atomicAdd(dst + 1, v * g.y);
        atomicAdd(dst + 2, v * g.z);
        atomicAdd(dst + 3, v * g.w);
    }
}

// ---------------- log_softmax rows (fused +b2): one wave per row ----------------
__global__ __launch_bounds__(256) void lsm_kernel(const float* __restrict__ oacc,
                                                  const float* __restrict__ b2,
                                                  float* __restrict__ out) {
    int wave = threadIdx.x >> 6;
    int lane = threadIdx.x & 63;
    int r = blockIdx.x * 4 + wave;
    if (r >= N_NODES) return;
    float v = -INFINITY;
    if (lane < OUT_DIM) v = oacc[r * OUT_DIM + lane] + b2[lane];
    float m = v;
#pragma unroll
    for (int off = 32; off; off >>= 1) m = fmaxf(m, __shfl_xor(m, off, 64));
    float ex = (lane < OUT_DIM) ? expf(v - m) : 0.f;
    float s = ex;
#pragma unroll
    for (int off = 32; off; off >>= 1) s += __shfl_xor(s, off, 64);
    if (lane < OUT_DIM) out[r * OUT_DIM + lane] = v - m - logf(s);
}

extern "C" void kernel_launch(void* const* d_in, const int* in_sizes, int n_in,
                              void* d_out, int out_size, void* d_ws, size_t ws_size,
                              hipStream_t stream) {
    const float* x    = (const float*)d_in[0];
    const int*   erow = (const int*)d_in[1];
    const int*   ecol = (const int*)d_in[2];
    const float* eval = (const float*)d_in[3];
    const float* W1   = (const float*)d_in[4];
    const float* b1   = (const float*)d_in[5];
    const float* W2   = (const float*)d_in[6];
    const float* b2   = (const float*)d_in[7];
    float* out = (float*)d_out;

    // workspace layout (floats): y1 | y2 | hacc | oacc  (hacc+oacc contiguous for one zero pass)
    float* ws   = (float*)d_ws;
    float* y1   = ws;                              // 40000*128 = 5,120,000
    float* y2   = y1 + (size_t)N_NODES * HID_DIM;  // 40000*40  = 1,600,000
    float* hacc = y2 + (size_t)N_NODES * OUT_DIM;  // 5,120,000
    float* oacc = hacc + (size_t)N_NODES * HID_DIM;// 1,600,000

    // zero the two scatter accumulators (6,720,000 floats = 1,680,000 float4)
    {
        int n4 = (N_NODES * HID_DIM + N_NODES * OUT_DIM) / 4;
        zero_kernel<<<(n4 + 255) / 256, 256, 0, stream>>>(hacc, n4);
    }
    gemm1_kernel<<<N_NODES / 64, 256, 0, stream>>>(x, W1, y1);
    spmm1_kernel<<<(N_EDGES * 32) / 256, 256, 0, stream>>>(erow, ecol, eval, y1, hacc);
    gemm2_kernel<<<N_NODES / 64, 64, 0, stream>>>(hacc, b1, W2, y2);
    spmm2_kernel<<<(N_EDGES * 10 + 255) / 256, 256, 0, stream>>>(erow, ecol, eval, y2, oacc);
    lsm_kernel<<<(N_NODES + 3) / 4, 256, 0, stream>>>(oacc, b2, out);
}

// Round 2
// 480.179 us; speedup vs baseline: 3.5669x; 3.5669x over previous
//
#include <hip/hip_runtime.h>
#include <math.h>

#define N_NODES 40000
#define N_EDGES 640000
#define IN_DIM 512
#define HID_DIM 128
#define OUT_DIM 40

// ---------------- zero counts (40000 ints = 10000 int4) ----------------
__global__ __launch_bounds__(256) void zero_counts_kernel(int* __restrict__ p) {
    int i = blockIdx.x * 256 + threadIdx.x;
    if (i < N_NODES / 4) {
        reinterpret_cast<int4*>(p)[i] = make_int4(0, 0, 0, 0);
    }
}

// ---------------- CSR build step 1: histogram of edge_row ----------------
__global__ __launch_bounds__(256) void hist_kernel(const int* __restrict__ erow,
                                                   int* __restrict__ counts) {
    int e = blockIdx.x * 256 + threadIdx.x;
    if (e < N_EDGES) atomicAdd(&counts[erow[e]], 1);
}

// ---------------- CSR build step 2: exclusive scan (single block) ----------------
// 1024 threads, chunk of 40 indices each (1024*40 = 40960 >= 40000).
__global__ __launch_bounds__(1024) void scan_kernel(const int* __restrict__ counts,
                                                    int* __restrict__ row_start,
                                                    int* __restrict__ cursor) {
    __shared__ int sdata[1024];
    const int t = threadIdx.x;
    const int base = t * 40;
    int sum = 0;
    for (int i = 0; i < 40; ++i) {
        int idx = base + i;
        if (idx < N_NODES) sum += counts[idx];
    }
    sdata[t] = sum;
    __syncthreads();
    // Hillis-Steele inclusive scan over 1024 partials
    for (int off = 1; off < 1024; off <<= 1) {
        int v = (t >= off) ? sdata[t - off] : 0;
        __syncthreads();
        sdata[t] += v;
        __syncthreads();
    }
    int run = (t == 0) ? 0 : sdata[t - 1];
    for (int i = 0; i < 40; ++i) {
        int idx = base + i;
        if (idx < N_NODES) {
            row_start[idx] = run;
            cursor[idx] = run;
            run += counts[idx];
        }
    }
    if (t == 0) row_start[N_NODES] = N_EDGES;
}

// ---------------- CSR build step 3: scatter edges into row-sorted order ----------------
__global__ __launch_bounds__(256) void scatter_kernel(const int* __restrict__ erow,
                                                      const int* __restrict__ ecol,
                                                      const float* __restrict__ eval,
                                                      int* __restrict__ cursor,
                                                      int2* __restrict__ sortedCV) {
    int e = blockIdx.x * 256 + threadIdx.x;
    if (e < N_EDGES) {
        int r = erow[e];
        int pos = atomicAdd(&cursor[r], 1);
        int2 cv;
        cv.x = ecol[e];
        cv.y = __float_as_int(eval[e]);
        sortedCV[pos] = cv;
    }
}

// ---------------- GEMM1: y1 = x @ W1  (40000x512 @ 512x128) ----------------
// 64x128 tile per block, 256 threads, 4x8 micro-tile per thread, BK=16.
__global__ __launch_bounds__(256) void gemm1_kernel(const float* __restrict__ x,
                                                    const float* __restrict__ W1,
                                                    float* __restrict__ y1) {
    __shared__ float As[16][68];    // [k][m], pad 68
    __shared__ float Bs[16][128];   // [k][n]
    const int m0 = blockIdx.x * 64;
    const int t  = threadIdx.x;
    const int tx = t & 15;          // col group (8 cols each)
    const int ty = t >> 4;          // row group (4 rows each)
    float acc[4][8] = {};

    for (int k0 = 0; k0 < IN_DIM; k0 += 16) {
        {
            int r = t >> 2;
            int c = (t & 3) * 4;
            float4 v = *reinterpret_cast<const float4*>(&x[(m0 + r) * IN_DIM + k0 + c]);
            As[c + 0][r] = v.x; As[c + 1][r] = v.y; As[c + 2][r] = v.z; As[c + 3][r] = v.w;
        }
        {
            int e  = t * 8;
            int kk = e >> 7;
            int nn = e & 127;
            const float* src = &W1[(k0 + kk) * HID_DIM + nn];
            float4 v0 = *reinterpret_cast<const float4*>(src);
            float4 v1 = *reinterpret_cast<const float4*>(src + 4);
            *reinterpret_cast<float4*>(&Bs[kk][nn])     = v0;
            *reinterpret_cast<float4*>(&Bs[kk][nn + 4]) = v1;
        }
        __syncthreads();
#pragma unroll
        for (int kk = 0; kk < 16; ++kk) {
            float a[4], b[8];
#pragma unroll
            for (int i = 0; i < 4; ++i) a[i] = As[kk][ty * 4 + i];
            float4 b0 = *reinterpret_cast<const float4*>(&Bs[kk][tx * 8]);
            float4 b1 = *reinterpret_cast<const float4*>(&Bs[kk][tx * 8 + 4]);
            b[0] = b0.x; b[1] = b0.y; b[2] = b0.z; b[3] = b0.w;
            b[4] = b1.x; b[5] = b1.y; b[6] = b1.z; b[7] = b1.w;
#pragma unroll
            for (int i = 0; i < 4; ++i)
#pragma unroll
                for (int j = 0; j < 8; ++j) acc[i][j] += a[i] * b[j];
        }
        __syncthreads();
    }
#pragma unroll
    for (int i = 0; i < 4; ++i) {
        int row = m0 + ty * 4 + i;
        float4 v0 = make_float4(acc[i][0], acc[i][1], acc[i][2], acc[i][3]);
        float4 v1 = make_float4(acc[i][4], acc[i][5], acc[i][6], acc[i][7]);
        *reinterpret_cast<float4*>(&y1[row * HID_DIM + tx * 8])     = v0;
        *reinterpret_cast<float4*>(&y1[row * HID_DIM + tx * 8 + 4]) = v1;
    }
}

// ---------------- SpMM1 (CSR): h[row] = relu(sum_e val*y1[col] + b1) ----------------
// One wave per row; 2 feats/lane (float2). Edge metadata loaded 64-at-a-time
// coalesced, broadcast via shfl (keeps gather loads independent across j).
__global__ __launch_bounds__(256) void spmm1_csr_kernel(const int* __restrict__ row_start,
                                                        const int2* __restrict__ sortedCV,
                                                        const float* __restrict__ y1,
                                                        const float* __restrict__ b1,
                                                        float* __restrict__ h) {
    const int lane = threadIdx.x & 63;
    const int row  = blockIdx.x * 4 + (threadIdx.x >> 6);
    const int s = row_start[row];
    const int e = row_start[row + 1];
    float2 acc = make_float2(0.f, 0.f);
    for (int base = s; base < e; base += 64) {
        int cnt = e - base; if (cnt > 64) cnt = 64;
        int cv_c = 0, cv_v = 0;
        if (lane < cnt) {
            int2 cv = sortedCV[base + lane];
            cv_c = cv.x; cv_v = cv.y;
        }
        for (int j = 0; j < cnt; ++j) {
            int   c = __shfl(cv_c, j, 64);
            float v = __int_as_float(__shfl(cv_v, j, 64));
            float2 g = *reinterpret_cast<const float2*>(&y1[c * HID_DIM + lane * 2]);
            acc.x += v * g.x;
            acc.y += v * g.y;
        }
    }
    float2 vb = *reinterpret_cast<const float2*>(&b1[lane * 2]);
    float2 o;
    o.x = fmaxf(acc.x + vb.x, 0.f);
    o.y = fmaxf(acc.y + vb.y, 0.f);
    *reinterpret_cast<float2*>(&h[row * HID_DIM + lane * 2]) = o;
}

// ---------------- GEMM2: y2 = h @ W2  (40000x128 @ 128x40) ----------------
__global__ __launch_bounds__(64) void gemm2_kernel(const float* __restrict__ h,
                                                   const float* __restrict__ W2,
                                                   float* __restrict__ y2) {
    __shared__ float hs[64][132];
    __shared__ float w2s[HID_DIM * OUT_DIM];
    const int m0 = blockIdx.x * 64;
    const int t  = threadIdx.x;

#pragma unroll
    for (int i = 0; i < 32; ++i) {
        int flat = i * 256 + t * 4;
        int row = flat >> 7;
        int col = flat & 127;
        *reinterpret_cast<float4*>(&hs[row][col]) =
            *reinterpret_cast<const float4*>(&h[(m0 + row) * HID_DIM + col]);
    }
#pragma unroll
    for (int i = 0; i < 20; ++i) {
        int flat = i * 256 + t * 4;
        *reinterpret_cast<float4*>(&w2s[flat]) =
            *reinterpret_cast<const float4*>(&W2[flat]);
    }
    __syncthreads();

    const int rl = t & 15;
    const int g  = t >> 4;
    float acc[4][10] = {};
#pragma unroll 4
    for (int k = 0; k < HID_DIM; ++k) {
        float a[4];
#pragma unroll
        for (int i = 0; i < 4; ++i) a[i] = hs[rl + 16 * i][k];
        float b[10];
#pragma unroll
        for (int j = 0; j < 10; j += 2) {
            float2 w = *reinterpret_cast<const float2*>(&w2s[k * OUT_DIM + g * 10 + j]);
            b[j] = w.x; b[j + 1] = w.y;
        }
#pragma unroll
        for (int i = 0; i < 4; ++i)
#pragma unroll
            for (int j = 0; j < 10; ++j) acc[i][j] += a[i] * b[j];
    }
#pragma unroll
    for (int i = 0; i < 4; ++i) {
        int row = m0 + rl + 16 * i;
#pragma unroll
        for (int j = 0; j < 10; j += 2) {
            float2 v = make_float2(acc[i][j], acc[i][j + 1]);
            *reinterpret_cast<float2*>(&y2[row * OUT_DIM + g * 10 + j]) = v;
        }
    }
}

// ---------------- SpMM2 (CSR) + bias + log_softmax fused ----------------
// One wave per row; lane<40 holds one output feature in a register.
__global__ __launch_bounds__(256) void spmm2_lsm_kernel(const int* __restrict__ row_start,
                                                        const int2* __restrict__ sortedCV,
                                                        const float* __restrict__ y2,
                                                        const float* __restrict__ b2,
                                                        float* __restrict__ out) {
    const int lane = threadIdx.x & 63;
    const int row  = blockIdx.x * 4 + (threadIdx.x >> 6);
    const int s = row_start[row];
    const int e = row_start[row + 1];
    float acc = 0.f;
    for (int base = s; base < e; base += 64) {
        int cnt = e - base; if (cnt > 64) cnt = 64;
        int cv_c = 0, cv_v = 0;
        if (lane < cnt) {
            int2 cv = sortedCV[base + lane];
            cv_c = cv.x; cv_v = cv.y;
        }
        for (int j = 0; j < cnt; ++j) {
            int   c = __shfl(cv_c, j, 64);
            float v = __int_as_float(__shfl(cv_v, j, 64));
            float g = (lane < OUT_DIM) ? y2[c * OUT_DIM + lane] : 0.f;
            acc += v * g;
        }
    }
    float val = (lane < OUT_DIM) ? (acc + b2[lane]) : -INFINITY;
    float m = val;
#pragma unroll
    for (int off = 32; off; off >>= 1) m = fmaxf(m, __shfl_xor(m, off, 64));
    float ex = (lane < OUT_DIM) ? expf(val - m) : 0.f;
    float sum = ex;
#pragma unroll
    for (int off = 32; off; off >>= 1) sum += __shfl_xor(sum, off, 64);
    if (lane < OUT_DIM) out[row * OUT_DIM + lane] = val - m - logf(sum);
}

extern "C" void kernel_launch(void* const* d_in, const int* in_sizes, int n_in,
                              void* d_out, int out_size, void* d_ws, size_t ws_size,
                              hipStream_t stream) {
    const float* x    = (const float*)d_in[0];
    const int*   erow = (const int*)d_in[1];
    const int*   ecol = (const int*)d_in[2];
    const float* eval = (const float*)d_in[3];
    const float* W1   = (const float*)d_in[4];
    const float* b1   = (const float*)d_in[5];
    const float* W2   = (const float*)d_in[6];
    const float* b2   = (const float*)d_in[7];
    float* out = (float*)d_out;

    // workspace layout (4-byte words):
    // y1[5.12M] | h[5.12M] | y2[1.6M] | sortedCV[1.28M int2] | counts[40k] | row_start[40001] | cursor[40k]
    float* ws       = (float*)d_ws;
    float* y1       = ws;
    float* h        = y1 + (size_t)N_NODES * HID_DIM;
    float* y2       = h  + (size_t)N_NODES * HID_DIM;
    int2*  sortedCV = (int2*)(y2 + (size_t)N_NODES * OUT_DIM);
    int*   counts   = (int*)(sortedCV + N_EDGES);
    int*   row_start= counts + N_NODES;
    int*   cursor   = row_start + (N_NODES + 1);

    // CSR build
    zero_counts_kernel<<<(N_NODES / 4 + 255) / 256, 256, 0, stream>>>(counts);
    hist_kernel<<<(N_EDGES + 255) / 256, 256, 0, stream>>>(erow, counts);
    scan_kernel<<<1, 1024, 0, stream>>>(counts, row_start, cursor);
    scatter_kernel<<<(N_EDGES + 255) / 256, 256, 0, stream>>>(erow, ecol, eval, cursor, sortedCV);

    // layer 1
    gemm1_kernel<<<N_NODES / 64, 256, 0, stream>>>(x, W1, y1);
    spmm1_csr_kernel<<<N_NODES / 4, 256, 0, stream>>>(row_start, sortedCV, y1, b1, h);

    // layer 2 (+ fused bias + log_softmax)
    gemm2_kernel<<<N_NODES / 64, 64, 0, stream>>>(h, W2, y2);
    spmm2_lsm_kernel<<<N_NODES / 4, 256, 0, stream>>>(row_start, sortedCV, y2, b2, out);
}

// Round 3
// 343.433 us; speedup vs baseline: 4.9872x; 1.3982x over previous
//
#include <hip/hip_runtime.h>
#include <math.h>

#define N_NODES 40000
#define N_EDGES 640000
#define IN_DIM 512
#define HID_DIM 128
#define OUT_DIM 40

typedef __attribute__((ext_vector_type(8))) short bf16x8_t;   // 8 bf16 = 4 VGPRs
typedef __attribute__((ext_vector_type(4))) float f32x4_t;    // MFMA accumulator

// fp32 -> bf16 bits, round-to-nearest-even
static __device__ __forceinline__ unsigned short f2bf(float f) {
    unsigned u = __float_as_uint(f);
    u += 0x7FFFu + ((u >> 16) & 1u);
    return (unsigned short)(u >> 16);
}

// ---------------- zero counts + total ----------------
__global__ __launch_bounds__(256) void zero_counts_kernel(int* __restrict__ counts,
                                                          int* __restrict__ total) {
    int i = blockIdx.x * 256 + threadIdx.x;
    if (i < N_NODES / 4) {
        reinterpret_cast<int4*>(counts)[i] = make_int4(0, 0, 0, 0);
    }
    if (i == 0) *total = 0;
}

// ---------------- histogram of edge_row ----------------
__global__ __launch_bounds__(256) void hist_kernel(const int* __restrict__ erow,
                                                   int* __restrict__ counts) {
    int e = blockIdx.x * 256 + threadIdx.x;
    if (e < N_EDGES) atomicAdd(&counts[erow[e]], 1);
}

// ---------------- segment allocation (replaces single-block scan) ----------------
// Per-wave shfl prefix over 64 counts, one global atomicAdd per wave.
// Segment order across rows is arbitrary — consumers use row_start + counts.
__global__ __launch_bounds__(256) void alloc_kernel(const int* __restrict__ counts,
                                                    int* __restrict__ total,
                                                    int* __restrict__ row_start,
                                                    int* __restrict__ cursor) {
    int i = blockIdx.x * 256 + threadIdx.x;
    int lane = threadIdx.x & 63;
    int cnt = (i < N_NODES) ? counts[i] : 0;
    int incl = cnt;
#pragma unroll
    for (int off = 1; off < 64; off <<= 1) {
        int v = __shfl_up(incl, off, 64);
        if (lane >= off) incl += v;
    }
    int wsum = __shfl(incl, 63, 64);
    int base = 0;
    if (lane == 63) base = atomicAdd(total, wsum);
    base = __shfl(base, 63, 64);
    if (i < N_NODES) {
        int s = base + incl - cnt;
        row_start[i] = s;
        cursor[i] = s;
    }
}

// ---------------- scatter edges into row-grouped order ----------------
__global__ __launch_bounds__(256) void scatter_kernel(const int* __restrict__ erow,
                                                      const int* __restrict__ ecol,
                                                      const float* __restrict__ eval,
                                                      int* __restrict__ cursor,
                                                      int2* __restrict__ sortedCV) {
    int e = blockIdx.x * 256 + threadIdx.x;
    if (e < N_EDGES) {
        int r = erow[e];
        int pos = atomicAdd(&cursor[r], 1);
        int2 cv;
        cv.x = ecol[e];
        cv.y = __float_as_int(eval[e]);
        sortedCV[pos] = cv;
    }
}

// ---------------- W1 [512x128] fp32 -> w1t [128x512] bf16 (transposed) ----------------
__global__ __launch_bounds__(256) void w1_convert_kernel(const float* __restrict__ W1,
                                                         unsigned short* __restrict__ w1t) {
    int idx = blockIdx.x * 256 + threadIdx.x;
    if (idx < IN_DIM * HID_DIM) {
        int k = idx >> 7;        // 0..511
        int n = idx & 127;       // coalesced read within W1 row
        w1t[n * IN_DIM + k] = f2bf(W1[idx]);
    }
}

// ---------------- GEMM1 (MFMA bf16): y1 = x @ W1  (40000x512 @ 512x128) ----------------
// Block: 256 thr (4 waves), 64 rows x 128 cols, BK=32.
// Wave w owns rows w*16..w*16+15, all 128 cols (8 n-tiles of 16x16x32 MFMA).
// LDS rows padded to 40 bf16 (80 B): b128 fragment reads are 2-way max (free).
__global__ __launch_bounds__(256) void gemm1_mfma_kernel(const float* __restrict__ x,
                                                         const unsigned short* __restrict__ w1t,
                                                         float* __restrict__ y1) {
    __shared__ unsigned short Al[64][40];    // A tile: 64 rows x 32 k
    __shared__ unsigned short Bl[128][40];   // B^T tile: 128 cols x 32 k
    const int t    = threadIdx.x;
    const int wave = t >> 6;
    const int lane = t & 63;
    const int m0   = blockIdx.x * 64;
    const int mrow = lane & 15;              // fragment row (A) / col (B,C)
    const int quad = lane >> 4;              // k-group of 8

    f32x4_t acc[8];
#pragma unroll
    for (int i = 0; i < 8; ++i) acc[i] = (f32x4_t){0.f, 0.f, 0.f, 0.f};

    for (int k0 = 0; k0 < IN_DIM; k0 += 32) {
        // stage A: 64x32 fp32 -> bf16. thread: row t>>2, k-offset (t&3)*8
        {
            int r = t >> 2;
            int c = (t & 3) * 8;
            const float* src = &x[(size_t)(m0 + r) * IN_DIM + k0 + c];
            float4 v0 = *reinterpret_cast<const float4*>(src);
            float4 v1 = *reinterpret_cast<const float4*>(src + 4);
            union { int4 v; unsigned short u[8]; } pk;
            pk.u[0] = f2bf(v0.x); pk.u[1] = f2bf(v0.y);
            pk.u[2] = f2bf(v0.z); pk.u[3] = f2bf(v0.w);
            pk.u[4] = f2bf(v1.x); pk.u[5] = f2bf(v1.y);
            pk.u[6] = f2bf(v1.z); pk.u[7] = f2bf(v1.w);
            *reinterpret_cast<int4*>(&Al[r][c]) = pk.v;
        }
        // stage B^T: 128 rows x 32 k bf16, 512 16B-chunks, 2 per thread
#pragma unroll
        for (int i = 0; i < 2; ++i) {
            int flat = i * 256 + t;          // 0..511
            int n  = flat >> 2;              // 0..127
            int kk = (flat & 3) * 8;
            *reinterpret_cast<int4*>(&Bl[n][kk]) =
                *reinterpret_cast<const int4*>(&w1t[(size_t)n * IN_DIM + k0 + kk]);
        }
        __syncthreads();

        bf16x8_t a = *reinterpret_cast<const bf16x8_t*>(&Al[wave * 16 + mrow][quad * 8]);
#pragma unroll
        for (int nt = 0; nt < 8; ++nt) {
            bf16x8_t b = *reinterpret_cast<const bf16x8_t*>(&Bl[nt * 16 + mrow][quad * 8]);
            acc[nt] = __builtin_amdgcn_mfma_f32_16x16x32_bf16(a, b, acc[nt], 0, 0, 0);
        }
        __syncthreads();
    }

    // C/D layout: col = lane&15, row = quad*4 + reg  [m89/m91 verified]
#pragma unroll
    for (int nt = 0; nt < 8; ++nt) {
#pragma unroll
        for (int reg = 0; reg < 4; ++reg) {
            int row = m0 + wave * 16 + quad * 4 + reg;
            y1[(size_t)row * HID_DIM + nt * 16 + mrow] = acc[nt][reg];
        }
    }
}

// ---------------- SpMM1 (CSR): h[row] = relu(sum_e val*y1[col] + b1) ----------------
__global__ __launch_bounds__(256) void spmm1_csr_kernel(const int* __restrict__ row_start,
                                                        const int* __restrict__ counts,
                                                        const int2* __restrict__ sortedCV,
                                                        const float* __restrict__ y1,
                                                        const float* __restrict__ b1,
                                                        float* __restrict__ h) {
    const int lane = threadIdx.x & 63;
    const int row  = blockIdx.x * 4 + (threadIdx.x >> 6);
    const int s = row_start[row];
    const int e = s + counts[row];
    float2 acc = make_float2(0.f, 0.f);
    for (int base = s; base < e; base += 64) {
        int cnt = e - base; if (cnt > 64) cnt = 64;
        int cv_c = 0, cv_v = 0;
        if (lane < cnt) {
            int2 cv = sortedCV[base + lane];
            cv_c = cv.x; cv_v = cv.y;
        }
        for (int j = 0; j < cnt; ++j) {
            int   c = __shfl(cv_c, j, 64);
            float v = __int_as_float(__shfl(cv_v, j, 64));
            float2 g = *reinterpret_cast<const float2*>(&y1[(size_t)c * HID_DIM + lane * 2]);
            acc.x += v * g.x;
            acc.y += v * g.y;
        }
    }
    float2 vb = *reinterpret_cast<const float2*>(&b1[lane * 2]);
    float2 o;
    o.x = fmaxf(acc.x + vb.x, 0.f);
    o.y = fmaxf(acc.y + vb.y, 0.f);
    *reinterpret_cast<float2*>(&h[(size_t)row * HID_DIM + lane * 2]) = o;
}

// ---------------- GEMM2: y2 = h @ W2  (40000x128 @ 128x40) ----------------
__global__ __launch_bounds__(64) void gemm2_kernel(const float* __restrict__ h,
                                                   const float* __restrict__ W2,
                                                   float* __restrict__ y2) {
    __shared__ float hs[64][132];
    __shared__ float w2s[HID_DIM * OUT_DIM];
    const int m0 = blockIdx.x * 64;
    const int t  = threadIdx.x;

#pragma unroll
    for (int i = 0; i < 32; ++i) {
        int flat = i * 256 + t * 4;
        int row = flat >> 7;
        int col = flat & 127;
        *reinterpret_cast<float4*>(&hs[row][col]) =
            *reinterpret_cast<const float4*>(&h[(size_t)(m0 + row) * HID_DIM + col]);
    }
#pragma unroll
    for (int i = 0; i < 20; ++i) {
        int flat = i * 256 + t * 4;
        *reinterpret_cast<float4*>(&w2s[flat]) =
            *reinterpret_cast<const float4*>(&W2[flat]);
    }
    __syncthreads();

    const int rl = t & 15;
    const int g  = t >> 4;
    float acc[4][10] = {};
#pragma unroll 4
    for (int k = 0; k < HID_DIM; ++k) {
        float a[4];
#pragma unroll
        for (int i = 0; i < 4; ++i) a[i] = hs[rl + 16 * i][k];
        float b[10];
#pragma unroll
        for (int j = 0; j < 10; j += 2) {
            float2 w = *reinterpret_cast<const float2*>(&w2s[k * OUT_DIM + g * 10 + j]);
            b[j] = w.x; b[j + 1] = w.y;
        }
#pragma unroll
        for (int i = 0; i < 4; ++i)
#pragma unroll
            for (int j = 0; j < 10; ++j) acc[i][j] += a[i] * b[j];
    }
#pragma unroll
    for (int i = 0; i < 4; ++i) {
        int row = m0 + rl + 16 * i;
#pragma unroll
        for (int j = 0; j < 10; j += 2) {
            float2 v = make_float2(acc[i][j], acc[i][j + 1]);
            *reinterpret_cast<float2*>(&y2[(size_t)row * OUT_DIM + g * 10 + j]) = v;
        }
    }
}

// ---------------- SpMM2 (CSR) + bias + log_softmax fused ----------------
__global__ __launch_bounds__(256) void spmm2_lsm_kernel(const int* __restrict__ row_start,
                                                        const int* __restrict__ counts,
                                                        const int2* __restrict__ sortedCV,
                                                        const float* __restrict__ y2,
                                                        const float* __restrict__ b2,
                                                        float* __restrict__ out) {
    const int lane = threadIdx.x & 63;
    const int row  = blockIdx.x * 4 + (threadIdx.x >> 6);
    const int s = row_start[row];
    const int e = s + counts[row];
    float acc = 0.f;
    for (int base = s; base < e; base += 64) {
        int cnt = e - base; if (cnt > 64) cnt = 64;
        int cv_c = 0, cv_v = 0;
        if (lane < cnt) {
            int2 cv = sortedCV[base + lane];
            cv_c = cv.x; cv_v = cv.y;
        }
        for (int j = 0; j < cnt; ++j) {
            int   c = __shfl(cv_c, j, 64);
            float v = __int_as_float(__shfl(cv_v, j, 64));
            float g = (lane < OUT_DIM) ? y2[(size_t)c * OUT_DIM + lane] : 0.f;
            acc += v * g;
        }
    }
    float val = (lane < OUT_DIM) ? (acc + b2[lane]) : -INFINITY;
    float m = val;
#pragma unroll
    for (int off = 32; off; off >>= 1) m = fmaxf(m, __shfl_xor(m, off, 64));
    float ex = (lane < OUT_DIM) ? expf(val - m) : 0.f;
    float sum = ex;
#pragma unroll
    for (int off = 32; off; off >>= 1) sum += __shfl_xor(sum, off, 64);
    if (lane < OUT_DIM) out[(size_t)row * OUT_DIM + lane] = val - m - logf(sum);
}

extern "C" void kernel_launch(void* const* d_in, const int* in_sizes, int n_in,
                              void* d_out, int out_size, void* d_ws, size_t ws_size,
                              hipStream_t stream) {
    const float* x    = (const float*)d_in[0];
    const int*   erow = (const int*)d_in[1];
    const int*   ecol = (const int*)d_in[2];
    const float* eval = (const float*)d_in[3];
    const float* W1   = (const float*)d_in[4];
    const float* b1   = (const float*)d_in[5];
    const float* W2   = (const float*)d_in[6];
    const float* b2   = (const float*)d_in[7];
    float* out = (float*)d_out;

    // workspace layout (4-byte words). y2 aliases y1 (y1 dead after spmm1).
    float* ws        = (float*)d_ws;
    float* y1        = ws;                                   // 5,120,000 (also y2)
    float* y2        = y1;
    float* h         = y1 + (size_t)N_NODES * HID_DIM;       // 5,120,000
    int2*  sortedCV  = (int2*)(h + (size_t)N_NODES * HID_DIM); // 1,280,000 int2
    int*   counts    = (int*)(sortedCV + N_EDGES);           // 40,000
    int*   row_start = counts + N_NODES;                     // 40,000
    int*   cursor    = row_start + N_NODES;                  // 40,000
    int*   total     = cursor + N_NODES;                     // 1 (+3 pad)
    unsigned short* w1t = (unsigned short*)(total + 4);      // 65,536 bf16 (16B aligned)

    // CSR build (scan-free)
    zero_counts_kernel<<<(N_NODES / 4 + 255) / 256, 256, 0, stream>>>(counts, total);
    hist_kernel<<<(N_EDGES + 255) / 256, 256, 0, stream>>>(erow, counts);
    alloc_kernel<<<(N_NODES + 255) / 256, 256, 0, stream>>>(counts, total, row_start, cursor);
    scatter_kernel<<<(N_EDGES + 255) / 256, 256, 0, stream>>>(erow, ecol, eval, cursor, sortedCV);

    // layer 1
    w1_convert_kernel<<<(IN_DIM * HID_DIM + 255) / 256, 256, 0, stream>>>(W1, w1t);
    gemm1_mfma_kernel<<<N_NODES / 64, 256, 0, stream>>>(x, w1t, y1);
    spmm1_csr_kernel<<<N_NODES / 4, 256, 0, stream>>>(row_start, counts, sortedCV, y1, b1, h);

    // layer 2 (+ fused bias + log_softmax)
    gemm2_kernel<<<N_NODES / 64, 64, 0, stream>>>(h, W2, y2);
    spmm2_lsm_kernel<<<N_NODES / 4, 256, 0, stream>>>(row_start, counts, sortedCV, y2, b2, out);
}

// Round 4
// 294.199 us; speedup vs baseline: 5.8218x; 1.1673x over previous
//
#include <hip/hip_runtime.h>
#include <math.h>

#define N_NODES 40000
#define N_EDGES 640000
#define IN_DIM 512
#define HID_DIM 128
#define OUT_DIM 40

typedef __attribute__((ext_vector_type(8))) short bf16x8_t;   // 8 bf16 = 4 VGPRs
typedef __attribute__((ext_vector_type(4))) float f32x4_t;    // MFMA accumulator

// fp32 -> bf16 bits, round-to-nearest-even
static __device__ __forceinline__ unsigned short f2bf(float f) {
    unsigned u = __float_as_uint(f);
    u += 0x7FFFu + ((u >> 16) & 1u);
    return (unsigned short)(u >> 16);
}
// unpack bf16 pair from a dword (little-endian: low ushort = even element)
static __device__ __forceinline__ float bflo(unsigned g) { return __uint_as_float(g << 16); }
static __device__ __forceinline__ float bfhi(unsigned g) { return __uint_as_float(g & 0xFFFF0000u); }
static __device__ __forceinline__ float bf1(unsigned short u) { return __uint_as_float(((unsigned)u) << 16); }

// ---------------- zero counts + total ----------------
__global__ __launch_bounds__(256) void zero_counts_kernel(int* __restrict__ counts,
                                                          int* __restrict__ total) {
    int i = blockIdx.x * 256 + threadIdx.x;
    if (i < N_NODES / 4) {
        reinterpret_cast<int4*>(counts)[i] = make_int4(0, 0, 0, 0);
    }
    if (i == 0) *total = 0;
}

// ---------------- histogram of edge_row ----------------
__global__ __launch_bounds__(256) void hist_kernel(const int* __restrict__ erow,
                                                   int* __restrict__ counts) {
    int e = blockIdx.x * 256 + threadIdx.x;
    if (e < N_EDGES) atomicAdd(&counts[erow[e]], 1);
}

// ---------------- segment allocation (scan-free) ----------------
__global__ __launch_bounds__(256) void alloc_kernel(const int* __restrict__ counts,
                                                    int* __restrict__ total,
                                                    int* __restrict__ row_start,
                                                    int* __restrict__ cursor) {
    int i = blockIdx.x * 256 + threadIdx.x;
    int lane = threadIdx.x & 63;
    int cnt = (i < N_NODES) ? counts[i] : 0;
    int incl = cnt;
#pragma unroll
    for (int off = 1; off < 64; off <<= 1) {
        int v = __shfl_up(incl, off, 64);
        if (lane >= off) incl += v;
    }
    int wsum = __shfl(incl, 63, 64);
    int base = 0;
    if (lane == 63) base = atomicAdd(total, wsum);
    base = __shfl(base, 63, 64);
    if (i < N_NODES) {
        int s = base + incl - cnt;
        row_start[i] = s;
        cursor[i] = s;
    }
}

// ---------------- scatter edges into row-grouped order ----------------
__global__ __launch_bounds__(256) void scatter_kernel(const int* __restrict__ erow,
                                                      const int* __restrict__ ecol,
                                                      const float* __restrict__ eval,
                                                      int* __restrict__ cursor,
                                                      int2* __restrict__ sortedCV) {
    int e = blockIdx.x * 256 + threadIdx.x;
    if (e < N_EDGES) {
        int r = erow[e];
        int pos = atomicAdd(&cursor[r], 1);
        int2 cv;
        cv.x = ecol[e];
        cv.y = __float_as_int(eval[e]);
        sortedCV[pos] = cv;
    }
}

// ---------------- W1 [512x128] fp32 -> w1t [128x512] bf16 (transposed) ----------------
__global__ __launch_bounds__(256) void w1_convert_kernel(const float* __restrict__ W1,
                                                         unsigned short* __restrict__ w1t) {
    int idx = blockIdx.x * 256 + threadIdx.x;
    if (idx < IN_DIM * HID_DIM) {
        int k = idx >> 7;
        int n = idx & 127;
        w1t[n * IN_DIM + k] = f2bf(W1[idx]);
    }
}

// ---------------- GEMM1 (MFMA bf16): y1b = bf16(x @ W1)  (40000x512 @ 512x128) ----------------
__global__ __launch_bounds__(256) void gemm1_mfma_kernel(const float* __restrict__ x,
                                                         const unsigned short* __restrict__ w1t,
                                                         unsigned short* __restrict__ y1b) {
    __shared__ unsigned short Al[64][40];    // A tile: 64 rows x 32 k (pad 40)
    __shared__ unsigned short Bl[128][40];   // B^T tile: 128 cols x 32 k
    const int t    = threadIdx.x;
    const int wave = t >> 6;
    const int lane = t & 63;
    const int m0   = blockIdx.x * 64;
    const int mrow = lane & 15;
    const int quad = lane >> 4;

    f32x4_t acc[8];
#pragma unroll
    for (int i = 0; i < 8; ++i) acc[i] = (f32x4_t){0.f, 0.f, 0.f, 0.f};

    for (int k0 = 0; k0 < IN_DIM; k0 += 32) {
        {
            int r = t >> 2;
            int c = (t & 3) * 8;
            const float* src = &x[(size_t)(m0 + r) * IN_DIM + k0 + c];
            float4 v0 = *reinterpret_cast<const float4*>(src);
            float4 v1 = *reinterpret_cast<const float4*>(src + 4);
            union { int4 v; unsigned short u[8]; } pk;
            pk.u[0] = f2bf(v0.x); pk.u[1] = f2bf(v0.y);
            pk.u[2] = f2bf(v0.z); pk.u[3] = f2bf(v0.w);
            pk.u[4] = f2bf(v1.x); pk.u[5] = f2bf(v1.y);
            pk.u[6] = f2bf(v1.z); pk.u[7] = f2bf(v1.w);
            *reinterpret_cast<int4*>(&Al[r][c]) = pk.v;
        }
#pragma unroll
        for (int i = 0; i < 2; ++i) {
            int flat = i * 256 + t;
            int n  = flat >> 2;
            int kk = (flat & 3) * 8;
            *reinterpret_cast<int4*>(&Bl[n][kk]) =
                *reinterpret_cast<const int4*>(&w1t[(size_t)n * IN_DIM + k0 + kk]);
        }
        __syncthreads();

        bf16x8_t a = *reinterpret_cast<const bf16x8_t*>(&Al[wave * 16 + mrow][quad * 8]);
#pragma unroll
        for (int nt = 0; nt < 8; ++nt) {
            bf16x8_t b = *reinterpret_cast<const bf16x8_t*>(&Bl[nt * 16 + mrow][quad * 8]);
            acc[nt] = __builtin_amdgcn_mfma_f32_16x16x32_bf16(a, b, acc[nt], 0, 0, 0);
        }
        __syncthreads();
    }

    // C/D layout: col = lane&15, row = quad*4 + reg
#pragma unroll
    for (int nt = 0; nt < 8; ++nt) {
#pragma unroll
        for (int reg = 0; reg < 4; ++reg) {
            int row = m0 + wave * 16 + quad * 4 + reg;
            y1b[(size_t)row * HID_DIM + nt * 16 + mrow] = f2bf(acc[nt][reg]);
        }
    }
}

// ---------------- SpMM1 (CSR): h[row] = relu(sum_e val*y1[col] + b1) ----------------
// One wave per row, 2 feats/lane (one dword of bf16x2). Gather loop unrolled x4
// so 4 independent L3 gathers are in flight per wave.
__global__ __launch_bounds__(256) void spmm1_csr_kernel(const int* __restrict__ row_start,
                                                        const int* __restrict__ counts,
                                                        const int2* __restrict__ sortedCV,
                                                        const unsigned short* __restrict__ y1b,
                                                        const float* __restrict__ b1,
                                                        float* __restrict__ h) {
    const int lane = threadIdx.x & 63;
    const int row  = blockIdx.x * 4 + (threadIdx.x >> 6);
    const int s = row_start[row];
    const int e = s + counts[row];
    float accx = 0.f, accy = 0.f;
    for (int base = s; base < e; base += 64) {
        int cnt = e - base; if (cnt > 64) cnt = 64;
        int cv_c = 0, cv_v = 0;
        if (lane < cnt) {
            int2 cv = sortedCV[base + lane];
            cv_c = cv.x; cv_v = cv.y;
        }
        int j = 0;
        for (; j + 4 <= cnt; j += 4) {
            int   c0 = __shfl(cv_c, j,     64);
            int   c1 = __shfl(cv_c, j + 1, 64);
            int   c2 = __shfl(cv_c, j + 2, 64);
            int   c3 = __shfl(cv_c, j + 3, 64);
            float v0 = __int_as_float(__shfl(cv_v, j,     64));
            float v1 = __int_as_float(__shfl(cv_v, j + 1, 64));
            float v2 = __int_as_float(__shfl(cv_v, j + 2, 64));
            float v3 = __int_as_float(__shfl(cv_v, j + 3, 64));
            unsigned g0 = *reinterpret_cast<const unsigned*>(&y1b[(size_t)c0 * HID_DIM + lane * 2]);
            unsigned g1 = *reinterpret_cast<const unsigned*>(&y1b[(size_t)c1 * HID_DIM + lane * 2]);
            unsigned g2 = *reinterpret_cast<const unsigned*>(&y1b[(size_t)c2 * HID_DIM + lane * 2]);
            unsigned g3 = *reinterpret_cast<const unsigned*>(&y1b[(size_t)c3 * HID_DIM + lane * 2]);
            accx += v0 * bflo(g0); accy += v0 * bfhi(g0);
            accx += v1 * bflo(g1); accy += v1 * bfhi(g1);
            accx += v2 * bflo(g2); accy += v2 * bfhi(g2);
            accx += v3 * bflo(g3); accy += v3 * bfhi(g3);
        }
        for (; j < cnt; ++j) {
            int   c = __shfl(cv_c, j, 64);
            float v = __int_as_float(__shfl(cv_v, j, 64));
            unsigned g = *reinterpret_cast<const unsigned*>(&y1b[(size_t)c * HID_DIM + lane * 2]);
            accx += v * bflo(g); accy += v * bfhi(g);
        }
    }
    float2 vb = *reinterpret_cast<const float2*>(&b1[lane * 2]);
    float2 o;
    o.x = fmaxf(accx + vb.x, 0.f);
    o.y = fmaxf(accy + vb.y, 0.f);
    *reinterpret_cast<float2*>(&h[(size_t)row * HID_DIM + lane * 2]) = o;
}

// ---------------- GEMM2: y2b = bf16(h @ W2)  (40000x128 @ 128x40) ----------------
__global__ __launch_bounds__(64) void gemm2_kernel(const float* __restrict__ h,
                                                   const float* __restrict__ W2,
                                                   unsigned short* __restrict__ y2b) {
    __shared__ float hs[64][132];
    __shared__ float w2s[HID_DIM * OUT_DIM];
    const int m0 = blockIdx.x * 64;
    const int t  = threadIdx.x;

#pragma unroll
    for (int i = 0; i < 32; ++i) {
        int flat = i * 256 + t * 4;
        int row = flat >> 7;
        int col = flat & 127;
        *reinterpret_cast<float4*>(&hs[row][col]) =
            *reinterpret_cast<const float4*>(&h[(size_t)(m0 + row) * HID_DIM + col]);
    }
#pragma unroll
    for (int i = 0; i < 20; ++i) {
        int flat = i * 256 + t * 4;
        *reinterpret_cast<float4*>(&w2s[flat]) =
            *reinterpret_cast<const float4*>(&W2[flat]);
    }
    __syncthreads();

    const int rl = t & 15;
    const int g  = t >> 4;
    float acc[4][10] = {};
#pragma unroll 4
    for (int k = 0; k < HID_DIM; ++k) {
        float a[4];
#pragma unroll
        for (int i = 0; i < 4; ++i) a[i] = hs[rl + 16 * i][k];
        float b[10];
#pragma unroll
        for (int j = 0; j < 10; j += 2) {
            float2 w = *reinterpret_cast<const float2*>(&w2s[k * OUT_DIM + g * 10 + j]);
            b[j] = w.x; b[j + 1] = w.y;
        }
#pragma unroll
        for (int i = 0; i < 4; ++i)
#pragma unroll
            for (int j = 0; j < 10; ++j) acc[i][j] += a[i] * b[j];
    }
#pragma unroll
    for (int i = 0; i < 4; ++i) {
        int row = m0 + rl + 16 * i;
#pragma unroll
        for (int j = 0; j < 10; j += 2) {
            unsigned pk = (unsigned)f2bf(acc[i][j]) | ((unsigned)f2bf(acc[i][j + 1]) << 16);
            *reinterpret_cast<unsigned*>(&y2b[(size_t)row * OUT_DIM + g * 10 + j]) = pk;
        }
    }
}

// ---------------- SpMM2 (CSR) + bias + log_softmax fused ----------------
__global__ __launch_bounds__(256) void spmm2_lsm_kernel(const int* __restrict__ row_start,
                                                        const int* __restrict__ counts,
                                                        const int2* __restrict__ sortedCV,
                                                        const unsigned short* __restrict__ y2b,
                                                        const float* __restrict__ b2,
                                                        float* __restrict__ out) {
    const int lane = threadIdx.x & 63;
    const int row  = blockIdx.x * 4 + (threadIdx.x >> 6);
    const int fl   = (lane < OUT_DIM) ? lane : 0;   // clamped feature index (in-bounds)
    const int s = row_start[row];
    const int e = s + counts[row];
    float acc = 0.f;
    for (int base = s; base < e; base += 64) {
        int cnt = e - base; if (cnt > 64) cnt = 64;
        int cv_c = 0, cv_v = 0;
        if (lane < cnt) {
            int2 cv = sortedCV[base + lane];
            cv_c = cv.x; cv_v = cv.y;
        }
        int j = 0;
        for (; j + 4 <= cnt; j += 4) {
            int   c0 = __shfl(cv_c, j,     64);
            int   c1 = __shfl(cv_c, j + 1, 64);
            int   c2 = __shfl(cv_c, j + 2, 64);
            int   c3 = __shfl(cv_c, j + 3, 64);
            float v0 = __int_as_float(__shfl(cv_v, j,     64));
            float v1 = __int_as_float(__shfl(cv_v, j + 1, 64));
            float v2 = __int_as_float(__shfl(cv_v, j + 2, 64));
            float v3 = __int_as_float(__shfl(cv_v, j + 3, 64));
            float g0 = bf1(y2b[(size_t)c0 * OUT_DIM + fl]);
            float g1 = bf1(y2b[(size_t)c1 * OUT_DIM + fl]);
            float g2 = bf1(y2b[(size_t)c2 * OUT_DIM + fl]);
            float g3 = bf1(y2b[(size_t)c3 * OUT_DIM + fl]);
            acc += v0 * g0 + v1 * g1 + v2 * g2 + v3 * g3;
        }
        for (; j < cnt; ++j) {
            int   c = __shfl(cv_c, j, 64);
            float v = __int_as_float(__shfl(cv_v, j, 64));
            acc += v * bf1(y2b[(size_t)c * OUT_DIM + fl]);
        }
    }
    float val = (lane < OUT_DIM) ? (acc + b2[lane]) : -INFINITY;
    float m = val;
#pragma unroll
    for (int off = 32; off; off >>= 1) m = fmaxf(m, __shfl_xor(m, off, 64));
    float ex = (lane < OUT_DIM) ? expf(val - m) : 0.f;
    float sum = ex;
#pragma unroll
    for (int off = 32; off; off >>= 1) sum += __shfl_xor(sum, off, 64);
    if (lane < OUT_DIM) out[(size_t)row * OUT_DIM + lane] = val - m - logf(sum);
}

extern "C" void kernel_launch(void* const* d_in, const int* in_sizes, int n_in,
                              void* d_out, int out_size, void* d_ws, size_t ws_size,
                              hipStream_t stream) {
    const float* x    = (const float*)d_in[0];
    const int*   erow = (const int*)d_in[1];
    const int*   ecol = (const int*)d_in[2];
    const float* eval = (const float*)d_in[3];
    const float* W1   = (const float*)d_in[4];
    const float* b1   = (const float*)d_in[5];
    const float* W2   = (const float*)d_in[6];
    const float* b2   = (const float*)d_in[7];
    float* out = (float*)d_out;

    // workspace layout (bytes, 16B-aligned regions):
    // h fp32 [40000*128] | sortedCV int2 [640000] | y1b bf16 [40000*128] |
    // y2b bf16 [40000*40] | counts | row_start | cursor | total | w1t bf16 [128*512]
    char* p = (char*)d_ws;
    float* h         = (float*)p;          p += (size_t)N_NODES * HID_DIM * 4;
    int2*  sortedCV  = (int2*)p;           p += (size_t)N_EDGES * 8;
    unsigned short* y1b = (unsigned short*)p; p += (size_t)N_NODES * HID_DIM * 2;
    unsigned short* y2b = (unsigned short*)p; p += (size_t)N_NODES * OUT_DIM * 2;
    int*   counts    = (int*)p;            p += (size_t)N_NODES * 4;
    int*   row_start = (int*)p;            p += (size_t)N_NODES * 4;
    int*   cursor    = (int*)p;            p += (size_t)N_NODES * 4;
    int*   total     = (int*)p;            p += 16;
    unsigned short* w1t = (unsigned short*)p;

    // CSR build (scan-free)
    zero_counts_kernel<<<(N_NODES / 4 + 255) / 256, 256, 0, stream>>>(counts, total);
    hist_kernel<<<(N_EDGES + 255) / 256, 256, 0, stream>>>(erow, counts);
    alloc_kernel<<<(N_NODES + 255) / 256, 256, 0, stream>>>(counts, total, row_start, cursor);
    scatter_kernel<<<(N_EDGES + 255) / 256, 256, 0, stream>>>(erow, ecol, eval, cursor, sortedCV);

    // layer 1
    w1_convert_kernel<<<(IN_DIM * HID_DIM + 255) / 256, 256, 0, stream>>>(W1, w1t);
    gemm1_mfma_kernel<<<N_NODES / 64, 256, 0, stream>>>(x, w1t, y1b);
    spmm1_csr_kernel<<<N_NODES / 4, 256, 0, stream>>>(row_start, counts, sortedCV, y1b, b1, h);

    // layer 2 (+ fused bias + log_softmax)
    gemm2_kernel<<<N_NODES / 64, 64, 0, stream>>>(h, W2, y2b);
    spmm2_lsm_kernel<<<N_NODES / 4, 256, 0, stream>>>(row_start, counts, sortedCV, y2b, b2, out);
}

// Round 5
// 280.279 us; speedup vs baseline: 6.1110x; 1.0497x over previous
//
#include <hip/hip_runtime.h>
#include <hip/hip_bf16.h>
#include <math.h>

#define N_NODES 40000
#define N_EDGES 640000
#define IN_DIM 512
#define HID_DIM 128
#define OUT_DIM 40
#define OUT_PAD 48   // y2 padded cols (MFMA n-tiles of 16)

typedef __attribute__((ext_vector_type(8))) short bf16x8_t;   // 8 bf16 = 4 VGPRs
typedef __attribute__((ext_vector_type(4))) float f32x4_t;    // MFMA accumulator

// fp32 -> bf16 bits, round-to-nearest-even (scalar)
static __device__ __forceinline__ unsigned short f2bf(float f) {
    unsigned u = __float_as_uint(f);
    u += 0x7FFFu + ((u >> 16) & 1u);
    return (unsigned short)(u >> 16);
}
static __device__ __forceinline__ float bf1(unsigned short u) { return __uint_as_float(((unsigned)u) << 16); }

// ---------------- zero counts + total ----------------
__global__ __launch_bounds__(256) void zero_counts_kernel(int* __restrict__ counts,
                                                          int* __restrict__ total) {
    int i = blockIdx.x * 256 + threadIdx.x;
    if (i < N_NODES / 4) {
        reinterpret_cast<int4*>(counts)[i] = make_int4(0, 0, 0, 0);
    }
    if (i == 0) *total = 0;
}

// ---------------- histogram of edge_row ----------------
__global__ __launch_bounds__(256) void hist_kernel(const int* __restrict__ erow,
                                                   int* __restrict__ counts) {
    int e = blockIdx.x * 256 + threadIdx.x;
    if (e < N_EDGES) atomicAdd(&counts[erow[e]], 1);
}

// ---------------- segment allocation (scan-free) ----------------
__global__ __launch_bounds__(256) void alloc_kernel(const int* __restrict__ counts,
                                                    int* __restrict__ total,
                                                    int* __restrict__ row_start,
                                                    int* __restrict__ cursor) {
    int i = blockIdx.x * 256 + threadIdx.x;
    int lane = threadIdx.x & 63;
    int cnt = (i < N_NODES) ? counts[i] : 0;
    int incl = cnt;
#pragma unroll
    for (int off = 1; off < 64; off <<= 1) {
        int v = __shfl_up(incl, off, 64);
        if (lane >= off) incl += v;
    }
    int wsum = __shfl(incl, 63, 64);
    int base = 0;
    if (lane == 63) base = atomicAdd(total, wsum);
    base = __shfl(base, 63, 64);
    if (i < N_NODES) {
        int s = base + incl - cnt;
        row_start[i] = s;
        cursor[i] = s;
    }
}

// ---------------- scatter edges into row-grouped order ----------------
__global__ __launch_bounds__(256) void scatter_kernel(const int* __restrict__ erow,
                                                      const int* __restrict__ ecol,
                                                      const float* __restrict__ eval,
                                                      int* __restrict__ cursor,
                                                      int2* __restrict__ sortedCV) {
    int e = blockIdx.x * 256 + threadIdx.x;
    if (e < N_EDGES) {
        int r = erow[e];
        int pos = atomicAdd(&cursor[r], 1);
        int2 cv;
        cv.x = ecol[e];
        cv.y = __float_as_int(eval[e]);
        sortedCV[pos] = cv;
    }
}

// ---------------- weight conversion: W1 -> w1t bf16 [128][512], W2 -> w2t bf16 [48][128] ----------------
__global__ __launch_bounds__(256) void convert_kernel(const float* __restrict__ W1,
                                                      const float* __restrict__ W2,
                                                      unsigned short* __restrict__ w1t,
                                                      unsigned short* __restrict__ w2t) {
    int idx = blockIdx.x * 256 + threadIdx.x;
    if (idx < IN_DIM * HID_DIM) {
        int k = idx >> 7;
        int n = idx & 127;
        w1t[n * IN_DIM + k] = f2bf(W1[idx]);
    } else if (idx < IN_DIM * HID_DIM + OUT_PAD * HID_DIM) {
        int j = idx - IN_DIM * HID_DIM;
        int n = j >> 7;          // padded out-col 0..47
        int k = j & 127;
        w2t[n * HID_DIM + k] = (n < OUT_DIM) ? f2bf(W2[k * OUT_DIM + n]) : 0;
    }
}

// ---------------- GEMM1 (MFMA bf16): y1b = bf16(x @ W1)  (40000x512 @ 512x128) ----------------
__global__ __launch_bounds__(256) void gemm1_mfma_kernel(const float* __restrict__ x,
                                                         const unsigned short* __restrict__ w1t,
                                                         unsigned short* __restrict__ y1b) {
    __shared__ unsigned short Al[64][40];    // A tile: 64 rows x 32 k (pad 40)
    __shared__ unsigned short Bl[128][40];   // B^T tile: 128 cols x 32 k
    const int t    = threadIdx.x;
    const int wave = t >> 6;
    const int lane = t & 63;
    const int m0   = blockIdx.x * 64;
    const int mrow = lane & 15;
    const int quad = lane >> 4;

    f32x4_t acc[8];
#pragma unroll
    for (int i = 0; i < 8; ++i) acc[i] = (f32x4_t){0.f, 0.f, 0.f, 0.f};

    for (int k0 = 0; k0 < IN_DIM; k0 += 32) {
        {
            int r = t >> 2;
            int c = (t & 3) * 8;
            const float* src = &x[(size_t)(m0 + r) * IN_DIM + k0 + c];
            float4 v0 = *reinterpret_cast<const float4*>(src);
            float4 v1 = *reinterpret_cast<const float4*>(src + 4);
            union { int4 v; __hip_bfloat162 b[4]; } pk;
            pk.b[0] = __float22bfloat162_rn(make_float2(v0.x, v0.y));
            pk.b[1] = __float22bfloat162_rn(make_float2(v0.z, v0.w));
            pk.b[2] = __float22bfloat162_rn(make_float2(v1.x, v1.y));
            pk.b[3] = __float22bfloat162_rn(make_float2(v1.z, v1.w));
            *reinterpret_cast<int4*>(&Al[r][c]) = pk.v;
        }
#pragma unroll
        for (int i = 0; i < 2; ++i) {
            int flat = i * 256 + t;
            int n  = flat >> 2;
            int kk = (flat & 3) * 8;
            *reinterpret_cast<int4*>(&Bl[n][kk]) =
                *reinterpret_cast<const int4*>(&w1t[(size_t)n * IN_DIM + k0 + kk]);
        }
        __syncthreads();

        bf16x8_t a = *reinterpret_cast<const bf16x8_t*>(&Al[wave * 16 + mrow][quad * 8]);
#pragma unroll
        for (int nt = 0; nt < 8; ++nt) {
            bf16x8_t b = *reinterpret_cast<const bf16x8_t*>(&Bl[nt * 16 + mrow][quad * 8]);
            acc[nt] = __builtin_amdgcn_mfma_f32_16x16x32_bf16(a, b, acc[nt], 0, 0, 0);
        }
        __syncthreads();
    }

    // C/D layout: col = lane&15, row = quad*4 + reg
#pragma unroll
    for (int nt = 0; nt < 8; ++nt) {
#pragma unroll
        for (int reg = 0; reg < 4; ++reg) {
            int row = m0 + wave * 16 + quad * 4 + reg;
            y1b[(size_t)row * HID_DIM + nt * 16 + mrow] = f2bf(acc[nt][reg]);
        }
    }
}

// ---------------- SpMM1 (CSR): h_bf[row] = bf16(relu(sum val*y1[col] + b1)) ----------------
// One wave per row; half-wave per edge (lanes 0-31 edge j, 32-63 edge j+1),
// dwordx2 gathers (4 bf16 feats/lane), 4 pairs (8 edges) unrolled per iteration.
__global__ __launch_bounds__(256) void spmm1_csr_kernel(const int* __restrict__ row_start,
                                                        const int* __restrict__ counts,
                                                        const int2* __restrict__ sortedCV,
                                                        const unsigned short* __restrict__ y1b,
                                                        const float* __restrict__ b1,
                                                        unsigned short* __restrict__ h_bf) {
    const int lane = threadIdx.x & 63;
    const int l32  = lane & 31;
    const int hh   = lane >> 5;                     // which edge of the pair
    const int row  = blockIdx.x * 4 + (threadIdx.x >> 6);
    const int s = row_start[row];
    const int e = s + counts[row];
    float a0 = 0.f, a1 = 0.f, a2 = 0.f, a3 = 0.f;   // feats 4*l32 .. 4*l32+3

    for (int base = s; base < e; base += 64) {
        int cnt = e - base; if (cnt > 64) cnt = 64;
        int cv_c = 0, cv_v = 0;
        if (lane < cnt) {
            int2 cv = sortedCV[base + lane];
            cv_c = cv.x; cv_v = cv.y;
        }
        int j = 0;
        for (; j + 8 <= cnt; j += 8) {
            int   c0 = __shfl(cv_c, j + 0 + hh, 64);
            int   c1 = __shfl(cv_c, j + 2 + hh, 64);
            int   c2 = __shfl(cv_c, j + 4 + hh, 64);
            int   c3 = __shfl(cv_c, j + 6 + hh, 64);
            float v0 = __int_as_float(__shfl(cv_v, j + 0 + hh, 64));
            float v1 = __int_as_float(__shfl(cv_v, j + 2 + hh, 64));
            float v2 = __int_as_float(__shfl(cv_v, j + 4 + hh, 64));
            float v3 = __int_as_float(__shfl(cv_v, j + 6 + hh, 64));
            uint2 g0 = *reinterpret_cast<const uint2*>(&y1b[(size_t)c0 * HID_DIM + l32 * 4]);
            uint2 g1 = *reinterpret_cast<const uint2*>(&y1b[(size_t)c1 * HID_DIM + l32 * 4]);
            uint2 g2 = *reinterpret_cast<const uint2*>(&y1b[(size_t)c2 * HID_DIM + l32 * 4]);
            uint2 g3 = *reinterpret_cast<const uint2*>(&y1b[(size_t)c3 * HID_DIM + l32 * 4]);
            a0 += v0 * __uint_as_float(g0.x << 16); a1 += v0 * __uint_as_float(g0.x & 0xFFFF0000u);
            a2 += v0 * __uint_as_float(g0.y << 16); a3 += v0 * __uint_as_float(g0.y & 0xFFFF0000u);
            a0 += v1 * __uint_as_float(g1.x << 16); a1 += v1 * __uint_as_float(g1.x & 0xFFFF0000u);
            a2 += v1 * __uint_as_float(g1.y << 16); a3 += v1 * __uint_as_float(g1.y & 0xFFFF0000u);
            a0 += v2 * __uint_as_float(g2.x << 16); a1 += v2 * __uint_as_float(g2.x & 0xFFFF0000u);
            a2 += v2 * __uint_as_float(g2.y << 16); a3 += v2 * __uint_as_float(g2.y & 0xFFFF0000u);
            a0 += v3 * __uint_as_float(g3.x << 16); a1 += v3 * __uint_as_float(g3.x & 0xFFFF0000u);
            a2 += v3 * __uint_as_float(g3.y << 16); a3 += v3 * __uint_as_float(g3.y & 0xFFFF0000u);
        }
        for (; j < cnt; j += 2) {
            int idx = j + hh;                        // idx<=63; lanes>=cnt hold v=0
            int   c = __shfl(cv_c, idx, 64);
            float v = __int_as_float(__shfl(cv_v, idx, 64));
            uint2 g = *reinterpret_cast<const uint2*>(&y1b[(size_t)c * HID_DIM + l32 * 4]);
            a0 += v * __uint_as_float(g.x << 16); a1 += v * __uint_as_float(g.x & 0xFFFF0000u);
            a2 += v * __uint_as_float(g.y << 16); a3 += v * __uint_as_float(g.y & 0xFFFF0000u);
        }
    }
    // combine the two half-wave partials
    a0 += __shfl_xor(a0, 32, 64);
    a1 += __shfl_xor(a1, 32, 64);
    a2 += __shfl_xor(a2, 32, 64);
    a3 += __shfl_xor(a3, 32, 64);
    if (hh == 0) {
        float4 vb = *reinterpret_cast<const float4*>(&b1[l32 * 4]);
        unsigned lo = (unsigned)f2bf(fmaxf(a0 + vb.x, 0.f)) |
                      ((unsigned)f2bf(fmaxf(a1 + vb.y, 0.f)) << 16);
        unsigned hi = (unsigned)f2bf(fmaxf(a2 + vb.z, 0.f)) |
                      ((unsigned)f2bf(fmaxf(a3 + vb.w, 0.f)) << 16);
        uint2 pk; pk.x = lo; pk.y = hi;
        *reinterpret_cast<uint2*>(&h_bf[(size_t)row * HID_DIM + l32 * 4]) = pk;
    }
}

// ---------------- GEMM2 (MFMA bf16): y2p = bf16(h @ W2)  (40000x128 @ 128x48pad) ----------------
__global__ __launch_bounds__(256) void gemm2_mfma_kernel(const unsigned short* __restrict__ h_bf,
                                                         const unsigned short* __restrict__ w2t,
                                                         unsigned short* __restrict__ y2p) {
    __shared__ unsigned short Hs[64][136];   // 64 rows x 128 k (pad 136)
    __shared__ unsigned short Ws[OUT_PAD][136];
    const int t    = threadIdx.x;
    const int wave = t >> 6;
    const int lane = t & 63;
    const int m0   = blockIdx.x * 64;
    const int mrow = lane & 15;
    const int quad = lane >> 4;

#pragma unroll
    for (int i = 0; i < 4; ++i) {               // 1024 16B chunks of H
        int flat = i * 256 + t;
        int r = flat >> 4;
        int c = (flat & 15) * 8;
        *reinterpret_cast<int4*>(&Hs[r][c]) =
            *reinterpret_cast<const int4*>(&h_bf[(size_t)(m0 + r) * HID_DIM + c]);
    }
#pragma unroll
    for (int i = 0; i < 3; ++i) {               // 768 16B chunks of W
        int flat = i * 256 + t;
        int n = flat >> 4;
        int c = (flat & 15) * 8;
        *reinterpret_cast<int4*>(&Ws[n][c]) =
            *reinterpret_cast<const int4*>(&w2t[(size_t)n * HID_DIM + c]);
    }
    __syncthreads();

    f32x4_t acc[3];
#pragma unroll
    for (int i = 0; i < 3; ++i) acc[i] = (f32x4_t){0.f, 0.f, 0.f, 0.f};
#pragma unroll
    for (int k0 = 0; k0 < HID_DIM; k0 += 32) {
        bf16x8_t a = *reinterpret_cast<const bf16x8_t*>(&Hs[wave * 16 + mrow][k0 + quad * 8]);
#pragma unroll
        for (int nt = 0; nt < 3; ++nt) {
            bf16x8_t b = *reinterpret_cast<const bf16x8_t*>(&Ws[nt * 16 + mrow][k0 + quad * 8]);
            acc[nt] = __builtin_amdgcn_mfma_f32_16x16x32_bf16(a, b, acc[nt], 0, 0, 0);
        }
    }
#pragma unroll
    for (int nt = 0; nt < 3; ++nt) {
#pragma unroll
        for (int reg = 0; reg < 4; ++reg) {
            int row = m0 + wave * 16 + quad * 4 + reg;
            y2p[(size_t)row * OUT_PAD + nt * 16 + mrow] = f2bf(acc[nt][reg]);
        }
    }
}

// ---------------- SpMM2 (CSR) + bias + log_softmax fused ----------------
__global__ __launch_bounds__(256) void spmm2_lsm_kernel(const int* __restrict__ row_start,
                                                        const int* __restrict__ counts,
                                                        const int2* __restrict__ sortedCV,
                                                        const unsigned short* __restrict__ y2p,
                                                        const float* __restrict__ b2,
                                                        float* __restrict__ out) {
    const int lane = threadIdx.x & 63;
    const int row  = blockIdx.x * 4 + (threadIdx.x >> 6);
    const int fl   = (lane < OUT_DIM) ? lane : 0;
    const int s = row_start[row];
    const int e = s + counts[row];
    float acc = 0.f;
    for (int base = s; base < e; base += 64) {
        int cnt = e - base; if (cnt > 64) cnt = 64;
        int cv_c = 0, cv_v = 0;
        if (lane < cnt) {
            int2 cv = sortedCV[base + lane];
            cv_c = cv.x; cv_v = cv.y;
        }
        int j = 0;
        for (; j + 8 <= cnt; j += 8) {
            int cc[8]; float vv[8]; float gg[8];
#pragma unroll
            for (int p = 0; p < 8; ++p) {
                cc[p] = __shfl(cv_c, j + p, 64);
                vv[p] = __int_as_float(__shfl(cv_v, j + p, 64));
            }
#pragma unroll
            for (int p = 0; p < 8; ++p) gg[p] = bf1(y2p[(size_t)cc[p] * OUT_PAD + fl]);
#pragma unroll
            for (int p = 0; p < 8; ++p) acc += vv[p] * gg[p];
        }
        for (; j < cnt; ++j) {
            int   c = __shfl(cv_c, j, 64);
            float v = __int_as_float(__shfl(cv_v, j, 64));
            acc += v * bf1(y2p[(size_t)c * OUT_PAD + fl]);
        }
    }
    float val = (lane < OUT_DIM) ? (acc + b2[lane]) : -INFINITY;
    float m = val;
#pragma unroll
    for (int off = 32; off; off >>= 1) m = fmaxf(m, __shfl_xor(m, off, 64));
    float ex = (lane < OUT_DIM) ? expf(val - m) : 0.f;
    float sum = ex;
#pragma unroll
    for (int off = 32; off; off >>= 1) sum += __shfl_xor(sum, off, 64);
    if (lane < OUT_DIM) out[(size_t)row * OUT_DIM + lane] = val - m - logf(sum);
}

extern "C" void kernel_launch(void* const* d_in, const int* in_sizes, int n_in,
                              void* d_out, int out_size, void* d_ws, size_t ws_size,
                              hipStream_t stream) {
    const float* x    = (const float*)d_in[0];
    const int*   erow = (const int*)d_in[1];
    const int*   ecol = (const int*)d_in[2];
    const float* eval = (const float*)d_in[3];
    const float* W1   = (const float*)d_in[4];
    const float* b1   = (const float*)d_in[5];
    const float* W2   = (const float*)d_in[6];
    const float* b2   = (const float*)d_in[7];
    float* out = (float*)d_out;

    // workspace layout (16B-aligned regions)
    char* p = (char*)d_ws;
    unsigned short* h_bf = (unsigned short*)p; p += (size_t)N_NODES * HID_DIM * 2;  // 10.24 MB
    int2*  sortedCV  = (int2*)p;               p += (size_t)N_EDGES * 8;            // 5.12 MB
    unsigned short* y1b = (unsigned short*)p;  p += (size_t)N_NODES * HID_DIM * 2;  // 10.24 MB
    unsigned short* y2p = (unsigned short*)p;  p += (size_t)N_NODES * OUT_PAD * 2;  // 3.84 MB
    int*   counts    = (int*)p;                p += (size_t)N_NODES * 4;
    int*   row_start = (int*)p;                p += (size_t)N_NODES * 4;
    int*   cursor    = (int*)p;                p += (size_t)N_NODES * 4;
    int*   total     = (int*)p;                p += 16;
    unsigned short* w1t = (unsigned short*)p;  p += (size_t)HID_DIM * IN_DIM * 2;   // 128 KB
    unsigned short* w2t = (unsigned short*)p;                                       // 12.3 KB

    // CSR build (scan-free)
    zero_counts_kernel<<<(N_NODES / 4 + 255) / 256, 256, 0, stream>>>(counts, total);
    hist_kernel<<<(N_EDGES + 255) / 256, 256, 0, stream>>>(erow, counts);
    alloc_kernel<<<(N_NODES + 255) / 256, 256, 0, stream>>>(counts, total, row_start, cursor);
    scatter_kernel<<<(N_EDGES + 255) / 256, 256, 0, stream>>>(erow, ecol, eval, cursor, sortedCV);

    // weight conversion (both layers, one launch)
    convert_kernel<<<(IN_DIM * HID_DIM + OUT_PAD * HID_DIM + 255) / 256, 256, 0, stream>>>(W1, W2, w1t, w2t);

    // layer 1
    gemm1_mfma_kernel<<<N_NODES / 64, 256, 0, stream>>>(x, w1t, y1b);
    spmm1_csr_kernel<<<N_NODES / 4, 256, 0, stream>>>(row_start, counts, sortedCV, y1b, b1, h_bf);

    // layer 2 (+ fused bias + log_softmax)
    gemm2_mfma_kernel<<<N_NODES / 64, 256, 0, stream>>>(h_bf, w2t, y2p);
    spmm2_lsm_kernel<<<N_NODES / 4, 256, 0, stream>>>(row_start, counts, sortedCV, y2p, b2, out);
}